// Round 1
// baseline (154.369 us; speedup 1.0000x reference)
//
#include <hip/hip_runtime.h>
#include <math.h>

#define NPTS  131072
#define NPRB  256          // pair blocks (0..255); blocks 0..7 also run setup first
#define NPTB  512          // point blocks (256..767)
#define GRID  (NPRB + NPTB)   // 768 = 256 CUs x 3 blocks -> co-resident (launch_bounds)
#define DLOG2PIF 58.8120661f
#define DLOG2PI  58.81206612467475
#define SHIFT 92.0f
#define NEGHALF_LOG2E -0.72134752044f
#define LOG2E 1.44269504089f
#define MAGIC 0x9E3779B9u

typedef __attribute__((ext_vector_type(8)))  short short8;
typedef __attribute__((ext_vector_type(16))) float f32x16;

static __device__ __forceinline__ unsigned bfh(float f) {    // fp32 -> bf16 bits (RNE)
  unsigned u = __float_as_uint(f);
  return (u + 0x7FFFu + ((u >> 16) & 1u)) >> 16;
}
static __device__ __forceinline__ float bfhf(float f) {
  return __uint_as_float(bfh(f) << 16);
}

// Fused kernel: setup (8 blocks, 1 cluster/wave) -> release 8 MAGIC flags;
// pair blocks need no setup output; point blocks overlap X load/convert with
// setup, then spin (relaxed polls + s_sleep), threadfence-acquire, and run the
// 32-cluster MFMA sweep with the a2-constant MFMA replaced by the amortized
// g = 2*At*A*mu matvec (folded c into Kc): 192 -> 136 MFMA/wave.
__global__ __launch_bounds__(256, 3) void fused_kernel(
    const float* __restrict__ X, const float* __restrict__ means,
    const float* __restrict__ chols, const float* __restrict__ wts,
    uint4* __restrict__ Afrag, float* __restrict__ gbuf,
    float* __restrict__ Kc, float* __restrict__ Sg,
    double* __restrict__ zterm, double* __restrict__ partials,
    unsigned* __restrict__ done, unsigned* __restrict__ ticket,
    float* __restrict__ out)
{
  __shared__ __align__(16) char smem[33792];  // setup: Ssh+bls 33.8KB / points: 2x16KB fsh / pairs: 16.9KB
  __shared__ float K2sh[32], sksh[32];
  __shared__ double redd[4], redz[4];
  __shared__ unsigned lastFlag;
  const int tid = threadIdx.x, wv = tid >> 6, lane = tid & 63;
  const int r = lane & 31, h = lane >> 5;

  if (blockIdx.x < NPRB) {
    // =========================== setup (blocks 0..7) ===========================
    if (blockIdx.x < 8) {
      const int k = blockIdx.x*4 + wv;            // one cluster per wave
      float* Ssh = (float*)smem + wv*1056;
      float* bls = (float*)smem + 4224 + wv*1056;
      if (blockIdx.x == 0 && tid == 0) *ticket = 0u;   // ordered before done[0] release
      const float* cp = chols + (size_t)k*1024 + r*32;
      float4 fa = *(const float4*)(cp + h*8);
      float4 fb = *(const float4*)(cp + h*8 + 4);
      float4 fc = *(const float4*)(cp + 16 + h*8);
      float4 fd = *(const float4*)(cp + 16 + h*8 + 4);
      float v0[8] = {fa.x,fa.y,fa.z,fa.w,fb.x,fb.y,fb.z,fb.w};
      float v1[8] = {fc.x,fc.y,fc.z,fc.w,fd.x,fd.y,fd.z,fd.w};
      short8 hi0, hi1, lo0, lo1;
      #pragma unroll
      for (int j = 0; j < 8; j++) {
        hi0[j] = (short)bfh(v0[j]);  lo0[j] = (short)bfh(v0[j] - bfhf(v0[j]));
        hi1[j] = (short)bfh(v1[j]);  lo1[j] = (short)bfh(v1[j] - bfhf(v1[j]));
      }
      f32x16 acc = {};
      acc = __builtin_amdgcn_mfma_f32_32x32x16_bf16(hi0, hi0, acc, 0,0,0);
      acc = __builtin_amdgcn_mfma_f32_32x32x16_bf16(hi1, hi1, acc, 0,0,0);
      acc = __builtin_amdgcn_mfma_f32_32x32x16_bf16(hi0, lo0, acc, 0,0,0);
      acc = __builtin_amdgcn_mfma_f32_32x32x16_bf16(hi1, lo1, acc, 0,0,0);
      acc = __builtin_amdgcn_mfma_f32_32x32x16_bf16(lo0, hi0, acc, 0,0,0);
      acc = __builtin_amdgcn_mfma_f32_32x32x16_bf16(lo1, hi1, acc, 0,0,0);
      #pragma unroll
      for (int q = 0; q < 16; q++) {
        int row = (q & 3) + 8*(q >> 2) + 4*h;
        Ssh[row*33 + r] = acc[q] + ((row == r) ? 1.0f : 0.0f);
      }
      float a[32];
      #pragma unroll
      for (int j = 0; j < 32; j++) a[j] = Ssh[r*33 + j];
      float ldsum = 0.0f;
      #pragma unroll
      for (int j = 0; j < 32; j++) {
        float dd = __shfl(a[j], j);
        float inv = __frsqrt_rn(dd);
        float sq = dd * inv;
        ldsum += __logf(sq);
        float l = a[j] * inv;
        #pragma unroll
        for (int e = j+1; e < 32; e++) {
          float le = __shfl(l, e);
          a[e] = (r >= e) ? fmaf(-l, le, a[e]) : a[e];
        }
        a[j] = (r == j) ? sq : ((r > j) ? l : a[j]);
      }
      #pragma unroll
      for (int j = 0; j < 32; j++) Ssh[r*33 + j] = a[j];
      #pragma unroll 1
      for (int d = 0; d < 32; d++) {       // column-parallel inversion, split accumulator
        float s0 = (d == r) ? 1.0f : 0.0f, s1 = 0.0f;
        int j = 0;
        for (; j + 1 < d; j += 2) {
          s0 = fmaf(-Ssh[d*33 + j],     bls[j*33 + r],     s0);
          s1 = fmaf(-Ssh[d*33 + j + 1], bls[(j+1)*33 + r], s1);
        }
        if (j < d) s0 = fmaf(-Ssh[d*33 + j], bls[j*33 + r], s0);
        bls[d*33 + r] = (s0 + s1) / Ssh[d*33 + d];
      }
      float t0[8], t1[8];
      #pragma unroll
      for (int j = 0; j < 8; j++) {
        t0[j] = bls[r*33 + h*8 + j];
        t1[j] = bls[r*33 + 16 + h*8 + j];
      }
      uint4 s0 = make_uint4(bfh(t0[0])|(bfh(t0[1])<<16), bfh(t0[2])|(bfh(t0[3])<<16),
                            bfh(t0[4])|(bfh(t0[5])<<16), bfh(t0[6])|(bfh(t0[7])<<16));
      uint4 s1 = make_uint4(bfh(t1[0])|(bfh(t1[1])<<16), bfh(t1[2])|(bfh(t1[3])<<16),
                            bfh(t1[4])|(bfh(t1[5])<<16), bfh(t1[6])|(bfh(t1[7])<<16));
      Afrag[(k*2 + 0)*64 + lane] = s0;
      Afrag[(k*2 + 1)*64 + lane] = s1;
      // g = 2*At~*A~*mu and c = ||A~ mu||^2, using the SAME bf16-rounded A~ as
      // the packed fragments so  ||A~x~||^2 - g.x~ + c == ||A~(x~-mu)||^2 exactly.
      const float* mk = means + k*32;
      float wr = 0.0f;
      #pragma unroll
      for (int j = 0; j < 32; j++) wr = fmaf(bfhf(bls[r*33 + j]), mk[j], wr);
      float c = wr*wr;
      #pragma unroll
      for (int off = 16; off > 0; off >>= 1) c += __shfl_xor(c, off);
      float gd = 0.0f;
      #pragma unroll
      for (int rr = 0; rr < 32; rr++)
        gd = fmaf(bfhf(bls[rr*33 + r]), __shfl(wr, rr), gd);
      if (h == 0) gbuf[k*32 + r] = 2.0f*gd;
      if (lane == 0) {
        float wk = wts[k];
        float ld2 = 2.0f*ldsum + DLOG2PIF;
        Kc[k] = LOG2E*(SHIFT - 0.5f*ld2 - 0.5f*c) + log2f(fabsf(wk));
        Sg[k] = (wk < 0.0f) ? -1.0f : 1.0f;
      }
      __syncthreads();                     // all waves' global stores drained (vmcnt at barrier)
      if (tid == 0) {
        __threadfence();                   // agent-scope release (L2 writeback for cross-XCD)
        __hip_atomic_store(&done[blockIdx.x], MAGIC, __ATOMIC_RELEASE,
                           __HIP_MEMORY_SCOPE_AGENT);
      }
      __syncthreads();                     // before pair work reuses smem
    }
    // =========================== pairs: 1 pair per wave ===========================
    {
      float* Ssh = (float*)smem + wv*1056;
      const int pid = blockIdx.x*4 + wv, pi = pid >> 5, pj = pid & 31;
      const float* cpi = chols + (size_t)pi*1024 + r*32;
      const float* cpj = chols + (size_t)pj*1024 + r*32;
      float4 ia = *(const float4*)(cpi + h*8);
      float4 ib = *(const float4*)(cpi + h*8 + 4);
      float4 ic = *(const float4*)(cpi + 16 + h*8);
      float4 id = *(const float4*)(cpi + 16 + h*8 + 4);
      float4 ja = *(const float4*)(cpj + h*8);
      float4 jb = *(const float4*)(cpj + h*8 + 4);
      float4 jc = *(const float4*)(cpj + 16 + h*8);
      float4 jd = *(const float4*)(cpj + 16 + h*8 + 4);
      float vi0[8] = {ia.x,ia.y,ia.z,ia.w,ib.x,ib.y,ib.z,ib.w};
      float vi1[8] = {ic.x,ic.y,ic.z,ic.w,id.x,id.y,id.z,id.w};
      float vj0[8] = {ja.x,ja.y,ja.z,ja.w,jb.x,jb.y,jb.z,jb.w};
      float vj1[8] = {jc.x,jc.y,jc.z,jc.w,jd.x,jd.y,jd.z,jd.w};
      short8 I0h,I0l,I1h,I1l,J0h,J0l,J1h,J1l;
      #pragma unroll
      for (int j = 0; j < 8; j++) {
        I0h[j]=(short)bfh(vi0[j]); I0l[j]=(short)bfh(vi0[j]-bfhf(vi0[j]));
        I1h[j]=(short)bfh(vi1[j]); I1l[j]=(short)bfh(vi1[j]-bfhf(vi1[j]));
        J0h[j]=(short)bfh(vj0[j]); J0l[j]=(short)bfh(vj0[j]-bfhf(vj0[j]));
        J1h[j]=(short)bfh(vj1[j]); J1l[j]=(short)bfh(vj1[j]-bfhf(vj1[j]));
      }
      f32x16 pacc = {};
      pacc = __builtin_amdgcn_mfma_f32_32x32x16_bf16(I0h, I0h, pacc, 0,0,0);
      pacc = __builtin_amdgcn_mfma_f32_32x32x16_bf16(I1h, I1h, pacc, 0,0,0);
      pacc = __builtin_amdgcn_mfma_f32_32x32x16_bf16(I0h, I0l, pacc, 0,0,0);
      pacc = __builtin_amdgcn_mfma_f32_32x32x16_bf16(I1h, I1l, pacc, 0,0,0);
      pacc = __builtin_amdgcn_mfma_f32_32x32x16_bf16(I0l, I0h, pacc, 0,0,0);
      pacc = __builtin_amdgcn_mfma_f32_32x32x16_bf16(I1l, I1h, pacc, 0,0,0);
      pacc = __builtin_amdgcn_mfma_f32_32x32x16_bf16(J0h, J0h, pacc, 0,0,0);
      pacc = __builtin_amdgcn_mfma_f32_32x32x16_bf16(J1h, J1h, pacc, 0,0,0);
      pacc = __builtin_amdgcn_mfma_f32_32x32x16_bf16(J0h, J0l, pacc, 0,0,0);
      pacc = __builtin_amdgcn_mfma_f32_32x32x16_bf16(J1h, J1l, pacc, 0,0,0);
      pacc = __builtin_amdgcn_mfma_f32_32x32x16_bf16(J0l, J0h, pacc, 0,0,0);
      pacc = __builtin_amdgcn_mfma_f32_32x32x16_bf16(J1l, J1h, pacc, 0,0,0);
      #pragma unroll
      for (int q = 0; q < 16; q++) {
        int row = (q & 3) + 8*(q >> 2) + 4*h;
        Ssh[row*33 + r] = pacc[q] + ((row == r) ? 2.0f : 0.0f);
      }
      float a[32];
      #pragma unroll
      for (int j = 0; j < 32; j++) a[j] = Ssh[r*33 + j];
      #pragma unroll
      for (int j = 0; j < 32; j++) {
        float dd = __shfl(a[j], j);
        float inv = __frsqrt_rn(dd);
        float sq = dd * inv;
        float l = a[j] * inv;
        #pragma unroll
        for (int e = j+1; e < 32; e++) {
          float le = __shfl(l, e);
          a[e] = (r >= e) ? fmaf(-l, le, a[e]) : a[e];
        }
        a[j] = (r == j) ? sq : ((r > j) ? l : a[j]);
      }
      float acc2 = means[pi*32 + r] - means[pj*32 + r];
      float maha = 0.0f, ldsum = 0.0f;
      #pragma unroll
      for (int d = 0; d < 32; d++) {
        float dd = __shfl(a[d], d);
        float yd = __shfl(acc2, d) / dd;
        maha = fmaf(yd, yd, maha);
        ldsum += __logf(dd);
        acc2 = (r > d) ? fmaf(-a[d], yd, acc2) : acc2;
      }
      if (lane == 0) {
        double vd = -0.5 * ((double)maha + 2.0*(double)ldsum + DLOG2PI);
        zterm[pid] = (double)wts[pi] * (double)wts[pj] * exp(vd);
      }
    }
    __syncthreads();
    if (tid == 0) {
      // acquire done[] so the end-ticket add is ordered after block0's ticket zero
      #pragma unroll 1
      for (int i = 0; i < 8; i++)
        while (__hip_atomic_load(&done[i], __ATOMIC_RELAXED,
                                 __HIP_MEMORY_SCOPE_AGENT) != MAGIC)
          __builtin_amdgcn_s_sleep(2);
      __threadfence();
      lastFlag = (atomicAdd(ticket, 1u) == GRID - 1) ? 1u : 0u;
    }
  } else {
    // =========================== points: 4 waves x 2 ptsets x 32 pts ===========================
    const int bp = blockIdx.x - NPRB;                  // 0..511
    uint4* fsh0 = (uint4*)smem;                        // 16KB phase buffer A
    uint4* fsh1 = (uint4*)smem + 1024;                 // 16KB phase buffer B
    const int n0 = bp*256 + wv*64 + r;                 // set0; set1 = n0+32
    short8 xh00, xh01, xh10, xh11;
    {
      const float* xp0 = X + (size_t)n0*32;
      const float* xp1 = X + (size_t)(n0+32)*32;
      float4 fa = *(const float4*)(xp0 + h*8);
      float4 fb = *(const float4*)(xp0 + h*8 + 4);
      float4 fc = *(const float4*)(xp0 + 16 + h*8);
      float4 fd = *(const float4*)(xp0 + 16 + h*8 + 4);
      float4 ga = *(const float4*)(xp1 + h*8);
      float4 gb = *(const float4*)(xp1 + h*8 + 4);
      float4 gc = *(const float4*)(xp1 + 16 + h*8);
      float4 gd = *(const float4*)(xp1 + 16 + h*8 + 4);
      float v00[8] = {fa.x,fa.y,fa.z,fa.w,fb.x,fb.y,fb.z,fb.w};
      float v01[8] = {fc.x,fc.y,fc.z,fc.w,fd.x,fd.y,fd.z,fd.w};
      float v10[8] = {ga.x,ga.y,ga.z,ga.w,gb.x,gb.y,gb.z,gb.w};
      float v11[8] = {gc.x,gc.y,gc.z,gc.w,gd.x,gd.y,gd.z,gd.w};
      #pragma unroll
      for (int j = 0; j < 8; j++) {
        xh00[j] = (short)bfh(v00[j]);  xh01[j] = (short)bfh(v01[j]);
        xh10[j] = (short)bfh(v10[j]);  xh11[j] = (short)bfh(v11[j]);
      }
    }
    // wait for setup (X loads above overlap the wait)
    if (tid < 8) {
      while (__hip_atomic_load(&done[tid], __ATOMIC_RELAXED,
                               __HIP_MEMORY_SCOPE_AGENT) != MAGIC)
        __builtin_amdgcn_s_sleep(8);
    }
    __syncthreads();
    __threadfence();                       // acquire: L1/L2 invalidate before reading setup output
    // phase-0 stage issue (regs), K2sh, G-matvec — all overlap
    uint4 p0a = Afrag[tid],       p0b = Afrag[tid + 256];
    uint4 p0c = Afrag[tid + 512], p0d = Afrag[tid + 768];
    if (tid < 32) { K2sh[tid] = Kc[tid]; sksh[tid] = Sg[tid]; }
    f32x16 accg0 = {}, accg1 = {};
    {
      const float* gp = gbuf + r*32 + h*8;
      float4 ga = *(const float4*)(gp);
      float4 gb = *(const float4*)(gp + 4);
      float4 gc = *(const float4*)(gp + 16);
      float4 gdv = *(const float4*)(gp + 20);
      float g0[8] = {ga.x,ga.y,ga.z,ga.w,gb.x,gb.y,gb.z,gb.w};
      float g1[8] = {gc.x,gc.y,gc.z,gc.w,gdv.x,gdv.y,gdv.z,gdv.w};
      short8 Gh0, Gl0, Gh1, Gl1;
      #pragma unroll
      for (int j = 0; j < 8; j++) {
        Gh0[j] = (short)bfh(g0[j]); Gl0[j] = (short)bfh(g0[j] - bfhf(g0[j]));
        Gh1[j] = (short)bfh(g1[j]); Gl1[j] = (short)bfh(g1[j] - bfhf(g1[j]));
      }
      accg0 = __builtin_amdgcn_mfma_f32_32x32x16_bf16(Gh0, xh00, accg0, 0,0,0);
      accg0 = __builtin_amdgcn_mfma_f32_32x32x16_bf16(Gl0, xh00, accg0, 0,0,0);
      accg0 = __builtin_amdgcn_mfma_f32_32x32x16_bf16(Gh1, xh01, accg0, 0,0,0);
      accg0 = __builtin_amdgcn_mfma_f32_32x32x16_bf16(Gl1, xh01, accg0, 0,0,0);
      accg1 = __builtin_amdgcn_mfma_f32_32x32x16_bf16(Gh0, xh10, accg1, 0,0,0);
      accg1 = __builtin_amdgcn_mfma_f32_32x32x16_bf16(Gl0, xh10, accg1, 0,0,0);
      accg1 = __builtin_amdgcn_mfma_f32_32x32x16_bf16(Gh1, xh11, accg1, 0,0,0);
      accg1 = __builtin_amdgcn_mfma_f32_32x32x16_bf16(Gl1, xh11, accg1, 0,0,0);
    }
    fsh0[tid] = p0a; fsh0[tid + 256] = p0b; fsh0[tid + 512] = p0c; fsh0[tid + 768] = p0d;
    __syncthreads();
    float sF0 = 0.0f, sF1 = 0.0f;
    #pragma unroll
    for (int ph = 0; ph < 4; ph++) {
      uint4 nx0, nx1, nx2, nx3;
      if (ph < 3) {                         // T14: issue next-phase loads before compute
        const uint4* srcA = Afrag + (ph + 1)*1024;
        nx0 = srcA[tid];       nx1 = srcA[tid + 256];
        nx2 = srcA[tid + 512]; nx3 = srcA[tid + 768];
      }
      const uint4* fsh = (ph & 1) ? fsh1 : fsh0;
      #pragma unroll
      for (int kk = 0; kk < 8; kk++) {
        const int kidx = ph*8 + kk;
        const short8* ap = (const short8*)(fsh + kk*128);
        short8 a0 = ap[lane], a1 = ap[64 + lane];
        const float Kk = K2sh[kidx], sk = sksh[kidx];
        f32x16 acc0 = {}, acc1 = {};
        acc0 = __builtin_amdgcn_mfma_f32_32x32x16_bf16(a0, xh00, acc0, 0,0,0);
        acc0 = __builtin_amdgcn_mfma_f32_32x32x16_bf16(a1, xh01, acc0, 0,0,0);
        acc1 = __builtin_amdgcn_mfma_f32_32x32x16_bf16(a0, xh10, acc1, 0,0,0);
        acc1 = __builtin_amdgcn_mfma_f32_32x32x16_bf16(a1, xh11, acc1, 0,0,0);
        float m0a=0.f, m0b=0.f, m1a=0.f, m1b=0.f;
        #pragma unroll
        for (int q = 0; q < 8; q++) {
          m0a = fmaf(acc0[q],   acc0[q],   m0a);
          m0b = fmaf(acc0[q+8], acc0[q+8], m0b);
          m1a = fmaf(acc1[q],   acc1[q],   m1a);
          m1b = fmaf(acc1[q+8], acc1[q+8], m1b);
        }
        // gx for cluster kidx lives in reg qg of the hneed half (C/D row mapping)
        const int qg = (kidx & 3) | (((kidx >> 3) & 3) << 2);
        const int hneed = (kidx >> 2) & 1;
        float m0 = m0a + m0b - ((h == hneed) ? accg0[qg] : 0.0f);
        float m1 = m1a + m1b - ((h == hneed) ? accg1[qg] : 0.0f);
        m0 += __shfl_xor(m0, 32);
        m1 += __shfl_xor(m1, 32);
        sF0 = fmaf(sk, exp2f(fmaf(m0, NEGHALF_LOG2E, Kk)), sF0);
        sF1 = fmaf(sk, exp2f(fmaf(m1, NEGHALF_LOG2E, Kk)), sF1);
      }
      if (ph < 3) {                         // ds_write after compute: load latency hidden
        uint4* nb = (ph & 1) ? fsh0 : fsh1;
        nb[tid] = nx0; nb[tid + 256] = nx1; nb[tid + 512] = nx2; nb[tid + 768] = nx3;
      }
      __syncthreads();
    }
    double Tp = (double)sF0*(double)sF0 + (double)sF1*(double)sF1;
    if (lane >= 32) Tp = 0.0;               // upper halves duplicate
    #pragma unroll
    for (int off = 32; off > 0; off >>= 1) Tp += __shfl_down(Tp, off);
    if (lane == 0) redd[wv] = Tp;
    __syncthreads();
    if (tid == 0) {
      partials[bp] = redd[0] + redd[1] + redd[2] + redd[3];
      __threadfence();
      lastFlag = (atomicAdd(ticket, 1u) == GRID - 1) ? 1u : 0u;
    }
  }
  // ======================= fused final in the last-arriving block =======================
  __syncthreads();
  if (lastFlag) {
    __threadfence();
    double t = 0.0, z = 0.0;
    for (int p = tid; p < NPTB; p += 256) t += partials[p];
    for (int p = tid; p < 1024; p += 256) z += zterm[p];
    #pragma unroll
    for (int off = 32; off > 0; off >>= 1) {
      t += __shfl_down(t, off);
      z += __shfl_down(z, off);
    }
    if (lane == 0) { redd[wv] = t; redz[wv] = z; }
    __syncthreads();
    if (tid == 0) {
      t = redd[0] + redd[1] + redd[2] + redd[3];
      z = redz[0] + redz[1] + redz[2] + redz[3];
      double logT = log(t) - 2.0*(double)SHIFT;
      double logz = log(z);
      out[0] = (float)((logz - logT) / (double)NPTS);
    }
  }
}

extern "C" void kernel_launch(void* const* d_in, const int* in_sizes, int n_in,
                              void* d_out, int out_size, void* d_ws, size_t ws_size,
                              hipStream_t stream) {
  const float* X     = (const float*)d_in[0];
  const float* means = (const float*)d_in[1];
  const float* chols = (const float*)d_in[2];
  const float* wts   = (const float*)d_in[3];
  float* out = (float*)d_out;
  char* ws = (char*)d_ws;
  uint4*    Afrag    = (uint4*)ws;                  // 65536
  float*    gbuf     = (float*)(ws + 65536);        // 4096  -> 69632
  float*    Kc       = (float*)(ws + 69632);        // 128   -> 69760
  float*    Sg       = (float*)(ws + 69760);        // 128   -> 69888
  double*   zterm    = (double*)(ws + 69888);       // 8192  -> 78080
  double*   partials = (double*)(ws + 78080);       // 4096  -> 82176
  unsigned* done     = (unsigned*)(ws + 82176);     // 32    -> 82208
  unsigned* ticket   = (unsigned*)(ws + 82208);     // 4     -> 82212

  fused_kernel<<<GRID, 256, 0, stream>>>(X, means, chols, wts, Afrag, gbuf, Kc, Sg,
                                         zterm, partials, done, ticket, out);
}

// Round 2
// 131.477 us; speedup vs baseline: 1.1741x; 1.1741x over previous
//
#include <hip/hip_runtime.h>
#include <math.h>

#define NPTS  131072
#define NPTB  1024         // point blocks: 256 thr = 4 waves x 32 pts = 128 pts/block
#define NPRB  256          // pair blocks: 4 pairs/block (1 per wave)
#define GRID  (NPTB + NPRB)   // 1280 = 5 blocks/CU
#define DLOG2PIF 58.8120661f
#define DLOG2PI  58.81206612467475
#define SHIFT 92.0f
#define NEGHALF_LOG2E -0.72134752044f
#define LOG2E 1.44269504089f

typedef __attribute__((ext_vector_type(8)))  short short8;
typedef __attribute__((ext_vector_type(16))) float f32x16;

static __device__ __forceinline__ unsigned bfh(float f) {    // fp32 -> bf16 bits (RNE)
  unsigned u = __float_as_uint(f);
  return (u + 0x7FFFu + ((u >> 16) & 1u)) >> 16;
}
static __device__ __forceinline__ float bfhf(float f) {
  return __uint_as_float(bfh(f) << 16);
}

// ===== setup: 8 blocks x 256 thr; wave wv handles cluster blockIdx*4+wv ============
// Sigma via 6 split-bf16 MFMAs; register chol (rsqrtf); REGISTER-recurrence
// triangular inversion (bv[32] fully unrolled: kills the per-column LDS
// write->read turnaround that serialized the old version).
__global__ __launch_bounds__(256) void setup_kernel(
    const float* __restrict__ means, const float* __restrict__ chols,
    const float* __restrict__ wts,
    uint4* __restrict__ Afrag, float* __restrict__ gbuf,
    float* __restrict__ Kc, float* __restrict__ Sg,
    unsigned* __restrict__ ticket)
{
  const int tid = threadIdx.x, wv = tid >> 6, lane = tid & 63;
  const int r = lane & 31, h = lane >> 5;
  const int k = blockIdx.x*4 + wv;
  __shared__ float SshA[4][1056];
  float* Ssh = SshA[wv];
  if (blockIdx.x == 0 && tid == 0) *ticket = 0u;
  const float* cp = chols + (size_t)k*1024 + r*32;
  float4 fa = *(const float4*)(cp + h*8);
  float4 fb = *(const float4*)(cp + h*8 + 4);
  float4 fc = *(const float4*)(cp + 16 + h*8);
  float4 fd = *(const float4*)(cp + 16 + h*8 + 4);
  float v0[8] = {fa.x,fa.y,fa.z,fa.w,fb.x,fb.y,fb.z,fb.w};
  float v1[8] = {fc.x,fc.y,fc.z,fc.w,fd.x,fd.y,fd.z,fd.w};
  short8 hi0, hi1, lo0, lo1;
  #pragma unroll
  for (int j = 0; j < 8; j++) {
    hi0[j] = (short)bfh(v0[j]);  lo0[j] = (short)bfh(v0[j] - bfhf(v0[j]));
    hi1[j] = (short)bfh(v1[j]);  lo1[j] = (short)bfh(v1[j] - bfhf(v1[j]));
  }
  f32x16 acc = {};
  acc = __builtin_amdgcn_mfma_f32_32x32x16_bf16(hi0, hi0, acc, 0,0,0);
  acc = __builtin_amdgcn_mfma_f32_32x32x16_bf16(hi1, hi1, acc, 0,0,0);
  acc = __builtin_amdgcn_mfma_f32_32x32x16_bf16(hi0, lo0, acc, 0,0,0);
  acc = __builtin_amdgcn_mfma_f32_32x32x16_bf16(hi1, lo1, acc, 0,0,0);
  acc = __builtin_amdgcn_mfma_f32_32x32x16_bf16(lo0, hi0, acc, 0,0,0);
  acc = __builtin_amdgcn_mfma_f32_32x32x16_bf16(lo1, hi1, acc, 0,0,0);
  #pragma unroll
  for (int q = 0; q < 16; q++) {
    int row = (q & 3) + 8*(q >> 2) + 4*h;
    Ssh[row*33 + r] = acc[q] + ((row == r) ? 1.0f : 0.0f);
  }
  float a[32];
  #pragma unroll
  for (int j = 0; j < 32; j++) a[j] = Ssh[r*33 + j];   // lane r holds row r
  float ldsum = 0.0f;
  #pragma unroll
  for (int j = 0; j < 32; j++) {
    float dd = __shfl(a[j], j);
    float inv = rsqrtf(dd);                            // fast v_rsq (chain-critical)
    float sq = dd * inv;
    ldsum += __logf(sq);
    float l = a[j] * inv;
    #pragma unroll
    for (int e = j+1; e < 32; e++) {
      float le = __shfl(l, e);
      a[e] = (r >= e) ? fmaf(-l, le, a[e]) : a[e];
    }
    a[j] = (r == j) ? sq : ((r > j) ? l : a[j]);
  }
  // L rows -> LDS (uniform broadcast reads in the inversion)
  #pragma unroll
  for (int j = 0; j < 32; j++) Ssh[r*33 + j] = a[j];
  // register-recurrence inversion: lane r owns column r of B = L^-1.
  // bv[j] == old bls[j*33+r]; fully unrolled -> static indices -> registers.
  float bv[32];
  #pragma unroll
  for (int d = 0; d < 32; d++) {
    float s0 = (d == r) ? 1.0f : 0.0f, s1 = 0.0f;
    #pragma unroll
    for (int j = 0; j + 1 < d; j += 2) {
      s0 = fmaf(-Ssh[d*33 + j],     bv[j],   s0);
      s1 = fmaf(-Ssh[d*33 + j + 1], bv[j+1], s1);
    }
    if (d & 1) s0 = fmaf(-Ssh[d*33 + (d-1)], bv[d-1], s0);
    bv[d] = __fdividef(s0 + s1, Ssh[d*33 + d]);
  }
  // B columns -> LDS so we can read rows for fragment packing
  #pragma unroll
  for (int d = 0; d < 32; d++) Ssh[d*33 + r] = bv[d];
  float t0[8], t1[8];
  #pragma unroll
  for (int j = 0; j < 8; j++) {
    t0[j] = Ssh[r*33 + h*8 + j];
    t1[j] = Ssh[r*33 + 16 + h*8 + j];
  }
  uint4 s0 = make_uint4(bfh(t0[0])|(bfh(t0[1])<<16), bfh(t0[2])|(bfh(t0[3])<<16),
                        bfh(t0[4])|(bfh(t0[5])<<16), bfh(t0[6])|(bfh(t0[7])<<16));
  uint4 s1 = make_uint4(bfh(t1[0])|(bfh(t1[1])<<16), bfh(t1[2])|(bfh(t1[3])<<16),
                        bfh(t1[4])|(bfh(t1[5])<<16), bfh(t1[6])|(bfh(t1[7])<<16));
  Afrag[(k*2 + 0)*64 + lane] = s0;
  Afrag[(k*2 + 1)*64 + lane] = s1;
  // g = 2*Ahi^T*Ahi*mu, c = ||Ahi mu||^2 — hi-only, CONSISTENT with the hi-only
  // fragments the point sweep consumes (verified numerics from round 1).
  const float* mk = means + k*32;
  float wr = 0.0f;
  #pragma unroll
  for (int j = 0; j < 32; j++) wr = fmaf(bfhf(Ssh[r*33 + j]), mk[j], wr);
  float c = wr*wr;
  #pragma unroll
  for (int off = 16; off > 0; off >>= 1) c += __shfl_xor(c, off);
  float gd = 0.0f;
  #pragma unroll
  for (int rr = 0; rr < 32; rr++)
    gd = fmaf(bfhf(bv[rr]), __shfl(wr, rr), gd);       // bv[rr] = B[rr][r]
  if (h == 0) gbuf[k*32 + r] = 2.0f*gd;
  if (lane == 0) {
    float wk = wts[k];
    float ld2 = 2.0f*ldsum + DLOG2PIF;
    Kc[k] = LOG2E*(SHIFT - 0.5f*ld2 - 0.5f*c) + log2f(fabsf(wk));
    Sg[k] = (wk < 0.0f) ? -1.0f : 1.0f;
  }
}

// ===== work: 1024 point blocks (32 pts/wave) + 256 pair blocks; fused final =======
// Point role: 16.5 KB LDS, ~80 VGPR -> 5 blocks/CU (20 waves/CU) vs old 12.
__global__ __launch_bounds__(256, 4) void work_kernel(
    const float* __restrict__ X, const float* __restrict__ means,
    const float* __restrict__ chols, const float* __restrict__ wts,
    const uint4* __restrict__ Afrag, const float* __restrict__ gbuf,
    const float* __restrict__ Kc, const float* __restrict__ Sg,
    double* __restrict__ zterm, double* __restrict__ partials,
    unsigned* __restrict__ ticket, float* __restrict__ out)
{
  __shared__ __align__(16) char smem[16896];   // points: 16 KB fsh / pairs: 16.9 KB
  __shared__ float K2sh[32], sksh[32];
  __shared__ double redd[4], redz[4];
  __shared__ unsigned lastFlag;
  const int tid = threadIdx.x, wv = tid >> 6, lane = tid & 63;
  const int r = lane & 31, h = lane >> 5;
  if (blockIdx.x < NPTB) {
    // =============== points: 4 waves x 32 pts, 32-cluster sweep ===============
    uint4* fsh = (uint4*)smem;
    if (tid < 32) { K2sh[tid] = Kc[tid]; sksh[tid] = Sg[tid]; }
    const int n0 = blockIdx.x*128 + wv*32 + r;
    short8 xh0, xh1;
    {
      const float* xp = X + (size_t)n0*32;
      float4 fa = *(const float4*)(xp + h*8);
      float4 fb = *(const float4*)(xp + h*8 + 4);
      float4 fc = *(const float4*)(xp + 16 + h*8);
      float4 fd = *(const float4*)(xp + 16 + h*8 + 4);
      float v0[8] = {fa.x,fa.y,fa.z,fa.w,fb.x,fb.y,fb.z,fb.w};
      float v1[8] = {fc.x,fc.y,fc.z,fc.w,fd.x,fd.y,fd.z,fd.w};
      #pragma unroll
      for (int j = 0; j < 8; j++) { xh0[j] = (short)bfh(v0[j]); xh1[j] = (short)bfh(v1[j]); }
    }
    // amortized g-matvec: accg[q] = g[cluster row(q,h)] . x~[col r]
    f32x16 accg = {};
    {
      const float* gp = gbuf + r*32 + h*8;
      float4 ga = *(const float4*)(gp);
      float4 gb = *(const float4*)(gp + 4);
      float4 gc = *(const float4*)(gp + 16);
      float4 gd = *(const float4*)(gp + 20);
      float g0[8] = {ga.x,ga.y,ga.z,ga.w,gb.x,gb.y,gb.z,gb.w};
      float g1[8] = {gc.x,gc.y,gc.z,gc.w,gd.x,gd.y,gd.z,gd.w};
      short8 Gh0, Gl0, Gh1, Gl1;
      #pragma unroll
      for (int j = 0; j < 8; j++) {
        Gh0[j] = (short)bfh(g0[j]); Gl0[j] = (short)bfh(g0[j] - bfhf(g0[j]));
        Gh1[j] = (short)bfh(g1[j]); Gl1[j] = (short)bfh(g1[j] - bfhf(g1[j]));
      }
      accg = __builtin_amdgcn_mfma_f32_32x32x16_bf16(Gh0, xh0, accg, 0,0,0);
      accg = __builtin_amdgcn_mfma_f32_32x32x16_bf16(Gl0, xh0, accg, 0,0,0);
      accg = __builtin_amdgcn_mfma_f32_32x32x16_bf16(Gh1, xh1, accg, 0,0,0);
      accg = __builtin_amdgcn_mfma_f32_32x32x16_bf16(Gl1, xh1, accg, 0,0,0);
    }
    float sF = 0.0f;
    #pragma unroll
    for (int ph = 0; ph < 4; ph++) {        // full unroll: accg[qg] stays static
      __syncthreads();                      // previous phase's readers done
      {
        const uint4* src = Afrag + ph*1024;
        uint4 t0 = src[tid], t1 = src[tid+256], t2 = src[tid+512], t3 = src[tid+768];
        fsh[tid] = t0; fsh[tid+256] = t1; fsh[tid+512] = t2; fsh[tid+768] = t3;
      }
      __syncthreads();
      const short8* cp0 = (const short8*)fsh;
      short8 c0 = cp0[lane], c1 = cp0[64 + lane];
      #pragma unroll
      for (int kk = 0; kk < 8; kk++) {
        short8 nf0, nf1;
        if (kk < 7) {                        // 1-deep fragment prefetch
          const short8* np = (const short8*)(fsh + (kk+1)*128);
          nf0 = np[lane]; nf1 = np[64 + lane];
        }
        const int kidx = ph*8 + kk;
        const float Kk = K2sh[kidx], sk = sksh[kidx];
        f32x16 acc2 = {};
        acc2 = __builtin_amdgcn_mfma_f32_32x32x16_bf16(c0, xh0, acc2, 0,0,0);
        acc2 = __builtin_amdgcn_mfma_f32_32x32x16_bf16(c1, xh1, acc2, 0,0,0);
        float ma = 0.f, mb = 0.f;
        #pragma unroll
        for (int q = 0; q < 8; q++) {
          ma = fmaf(acc2[q],   acc2[q],   ma);
          mb = fmaf(acc2[q+8], acc2[q+8], mb);
        }
        const int qg = (kidx & 3) | (((kidx >> 3) & 3) << 2);
        const int hneed = (kidx >> 2) & 1;
        float m = ma + mb - ((h == hneed) ? accg[qg] : 0.0f);
        m += __shfl_xor(m, 32);
        sF = fmaf(sk, exp2f(fmaf(m, NEGHALF_LOG2E, Kk)), sF);
        c0 = nf0; c1 = nf1;
      }
    }
    double Tp = (double)sF*(double)sF;
    if (lane >= 32) Tp = 0.0;                // upper half duplicates columns
    #pragma unroll
    for (int off = 32; off > 0; off >>= 1) Tp += __shfl_down(Tp, off);
    if (lane == 0) redd[wv] = Tp;
    __syncthreads();
    if (tid == 0) partials[blockIdx.x] = redd[0] + redd[1] + redd[2] + redd[3];
  } else {
    // ================= pairs: 1 pair per wave, from chols ==================
    float* Ssh = (float*)smem + wv*1056;
    const int pid = (blockIdx.x - NPTB)*4 + wv, pi = pid >> 5, pj = pid & 31;
    const float* cpi = chols + (size_t)pi*1024 + r*32;
    const float* cpj = chols + (size_t)pj*1024 + r*32;
    float4 ia = *(const float4*)(cpi + h*8);
    float4 ib = *(const float4*)(cpi + h*8 + 4);
    float4 ic = *(const float4*)(cpi + 16 + h*8);
    float4 id = *(const float4*)(cpi + 16 + h*8 + 4);
    float4 ja = *(const float4*)(cpj + h*8);
    float4 jb = *(const float4*)(cpj + h*8 + 4);
    float4 jc = *(const float4*)(cpj + 16 + h*8);
    float4 jd = *(const float4*)(cpj + 16 + h*8 + 4);
    float vi0[8] = {ia.x,ia.y,ia.z,ia.w,ib.x,ib.y,ib.z,ib.w};
    float vi1[8] = {ic.x,ic.y,ic.z,ic.w,id.x,id.y,id.z,id.w};
    float vj0[8] = {ja.x,ja.y,ja.z,ja.w,jb.x,jb.y,jb.z,jb.w};
    float vj1[8] = {jc.x,jc.y,jc.z,jc.w,jd.x,jd.y,jd.z,jd.w};
    short8 I0h,I0l,I1h,I1l,J0h,J0l,J1h,J1l;
    #pragma unroll
    for (int j = 0; j < 8; j++) {
      I0h[j]=(short)bfh(vi0[j]); I0l[j]=(short)bfh(vi0[j]-bfhf(vi0[j]));
      I1h[j]=(short)bfh(vi1[j]); I1l[j]=(short)bfh(vi1[j]-bfhf(vi1[j]));
      J0h[j]=(short)bfh(vj0[j]); J0l[j]=(short)bfh(vj0[j]-bfhf(vj0[j]));
      J1h[j]=(short)bfh(vj1[j]); J1l[j]=(short)bfh(vj1[j]-bfhf(vj1[j]));
    }
    f32x16 pacc = {};
    pacc = __builtin_amdgcn_mfma_f32_32x32x16_bf16(I0h, I0h, pacc, 0,0,0);
    pacc = __builtin_amdgcn_mfma_f32_32x32x16_bf16(I1h, I1h, pacc, 0,0,0);
    pacc = __builtin_amdgcn_mfma_f32_32x32x16_bf16(I0h, I0l, pacc, 0,0,0);
    pacc = __builtin_amdgcn_mfma_f32_32x32x16_bf16(I1h, I1l, pacc, 0,0,0);
    pacc = __builtin_amdgcn_mfma_f32_32x32x16_bf16(I0l, I0h, pacc, 0,0,0);
    pacc = __builtin_amdgcn_mfma_f32_32x32x16_bf16(I1l, I1h, pacc, 0,0,0);
    pacc = __builtin_amdgcn_mfma_f32_32x32x16_bf16(J0h, J0h, pacc, 0,0,0);
    pacc = __builtin_amdgcn_mfma_f32_32x32x16_bf16(J1h, J1h, pacc, 0,0,0);
    pacc = __builtin_amdgcn_mfma_f32_32x32x16_bf16(J0h, J0l, pacc, 0,0,0);
    pacc = __builtin_amdgcn_mfma_f32_32x32x16_bf16(J1h, J1l, pacc, 0,0,0);
    pacc = __builtin_amdgcn_mfma_f32_32x32x16_bf16(J0l, J0h, pacc, 0,0,0);
    pacc = __builtin_amdgcn_mfma_f32_32x32x16_bf16(J1l, J1h, pacc, 0,0,0);
    #pragma unroll
    for (int q = 0; q < 16; q++) {
      int row = (q & 3) + 8*(q >> 2) + 4*h;
      Ssh[row*33 + r] = pacc[q] + ((row == r) ? 2.0f : 0.0f);
    }
    float a[32];
    #pragma unroll
    for (int j = 0; j < 32; j++) a[j] = Ssh[r*33 + j];
    #pragma unroll
    for (int j = 0; j < 32; j++) {
      float dd = __shfl(a[j], j);
      float inv = __frsqrt_rn(dd);
      float sq = dd * inv;
      float l = a[j] * inv;
      #pragma unroll
      for (int e = j+1; e < 32; e++) {
        float le = __shfl(l, e);
        a[e] = (r >= e) ? fmaf(-l, le, a[e]) : a[e];
      }
      a[j] = (r == j) ? sq : ((r > j) ? l : a[j]);
    }
    float acc2 = means[pi*32 + r] - means[pj*32 + r];
    float maha = 0.0f, ldsum = 0.0f;
    #pragma unroll
    for (int d = 0; d < 32; d++) {
      float dd = __shfl(a[d], d);
      float yd = __shfl(acc2, d) / dd;
      maha = fmaf(yd, yd, maha);
      ldsum += __logf(dd);
      acc2 = (r > d) ? fmaf(-a[d], yd, acc2) : acc2;
    }
    if (lane == 0) {
      double vd = -0.5 * ((double)maha + 2.0*(double)ldsum + DLOG2PI);
      zterm[pid] = (double)wts[pi] * (double)wts[pj] * exp(vd);
    }
  }
  // ================= end-of-kernel ticket + fused final ====================
  __syncthreads();
  if (tid == 0) {
    __threadfence();
    lastFlag = (atomicAdd(ticket, 1u) == GRID - 1) ? 1u : 0u;
  }
  __syncthreads();
  if (lastFlag) {
    __threadfence();
    double t = 0.0, z = 0.0;
    for (int p = tid; p < NPTB; p += 256) t += partials[p];
    for (int p = tid; p < 1024; p += 256) z += zterm[p];
    #pragma unroll
    for (int off = 32; off > 0; off >>= 1) {
      t += __shfl_down(t, off);
      z += __shfl_down(z, off);
    }
    if (lane == 0) { redd[wv] = t; redz[wv] = z; }
    __syncthreads();
    if (tid == 0) {
      t = redd[0] + redd[1] + redd[2] + redd[3];
      z = redz[0] + redz[1] + redz[2] + redz[3];
      double logT = log(t) - 2.0*(double)SHIFT;
      double logz = log(z);
      out[0] = (float)((logz - logT) / (double)NPTS);
    }
  }
}

extern "C" void kernel_launch(void* const* d_in, const int* in_sizes, int n_in,
                              void* d_out, int out_size, void* d_ws, size_t ws_size,
                              hipStream_t stream) {
  const float* X     = (const float*)d_in[0];
  const float* means = (const float*)d_in[1];
  const float* chols = (const float*)d_in[2];
  const float* wts   = (const float*)d_in[3];
  float* out = (float*)d_out;
  char* ws = (char*)d_ws;
  uint4*    Afrag    = (uint4*)ws;                  // 65536
  float*    gbuf     = (float*)(ws + 65536);        // 4096  -> 69632
  float*    Kc       = (float*)(ws + 69632);        // 128   -> 69760
  float*    Sg       = (float*)(ws + 69760);        // 128   -> 69888
  double*   zterm    = (double*)(ws + 69888);       // 8192  -> 78080
  double*   partials = (double*)(ws + 78080);       // 8192  -> 86272
  unsigned* ticket   = (unsigned*)(ws + 86272);     // 4     -> 86276

  setup_kernel<<<8, 256, 0, stream>>>(means, chols, wts, Afrag, gbuf, Kc, Sg, ticket);
  work_kernel<<<GRID, 256, 0, stream>>>(X, means, chols, wts, Afrag, gbuf, Kc, Sg,
                                        zterm, partials, ticket, out);
}

// Round 3
// 117.121 us; speedup vs baseline: 1.3180x; 1.1226x over previous
//
#include <hip/hip_runtime.h>
#include <math.h>

#define NPTS  131072
#define NPTB  512          // point blocks: 256 thr = 4 waves x 2 sets x 32 pts
#define NPRB  256          // pair blocks folded into setup kernel (blocks 8..263)
#define GRIDW NPTB         // work-kernel grid (points only)
#define DLOG2PIF 58.8120661f
#define DLOG2PI  58.81206612467475
#define SHIFT 92.0f
#define NEGHALF_LOG2E -0.72134752044f
#define LOG2E 1.44269504089f

typedef __attribute__((ext_vector_type(8)))  short short8;
typedef __attribute__((ext_vector_type(16))) float f32x16;

static __device__ __forceinline__ unsigned bfh(float f) {    // fp32 -> bf16 bits (RNE)
  unsigned u = __float_as_uint(f);
  return (u + 0x7FFFu + ((u >> 16) & 1u)) >> 16;
}
static __device__ __forceinline__ float bfhf(float f) {
  return __uint_as_float(bfh(f) << 16);
}

// ===== kernel 1: setup (blocks 0..7, 1 cluster/wave) + pairs (blocks 8..263) ======
// Pairs depend only on inputs -> they overlap setup's serial Cholesky window.
__global__ __launch_bounds__(256) void setup_kernel(
    const float* __restrict__ means, const float* __restrict__ chols,
    const float* __restrict__ wts,
    uint4* __restrict__ Afrag, float* __restrict__ gbuf,
    float* __restrict__ Kc, float* __restrict__ Sg,
    double* __restrict__ zterm, unsigned* __restrict__ ticket)
{
  const int tid = threadIdx.x, wv = tid >> 6, lane = tid & 63;
  const int r = lane & 31, h = lane >> 5;
  __shared__ float SshA[4][1056];
  float* Ssh = SshA[wv];
  if (blockIdx.x < 8) {
    // --------------------------- setup role ---------------------------
    const int k = blockIdx.x*4 + wv;
    if (blockIdx.x == 0 && tid == 0) *ticket = 0u;
    const float* cp = chols + (size_t)k*1024 + r*32;
    float4 fa = *(const float4*)(cp + h*8);
    float4 fb = *(const float4*)(cp + h*8 + 4);
    float4 fc = *(const float4*)(cp + 16 + h*8);
    float4 fd = *(const float4*)(cp + 16 + h*8 + 4);
    float v0[8] = {fa.x,fa.y,fa.z,fa.w,fb.x,fb.y,fb.z,fb.w};
    float v1[8] = {fc.x,fc.y,fc.z,fc.w,fd.x,fd.y,fd.z,fd.w};
    short8 hi0, hi1, lo0, lo1;
    #pragma unroll
    for (int j = 0; j < 8; j++) {
      hi0[j] = (short)bfh(v0[j]);  lo0[j] = (short)bfh(v0[j] - bfhf(v0[j]));
      hi1[j] = (short)bfh(v1[j]);  lo1[j] = (short)bfh(v1[j] - bfhf(v1[j]));
    }
    f32x16 acc = {};
    acc = __builtin_amdgcn_mfma_f32_32x32x16_bf16(hi0, hi0, acc, 0,0,0);
    acc = __builtin_amdgcn_mfma_f32_32x32x16_bf16(hi1, hi1, acc, 0,0,0);
    acc = __builtin_amdgcn_mfma_f32_32x32x16_bf16(hi0, lo0, acc, 0,0,0);
    acc = __builtin_amdgcn_mfma_f32_32x32x16_bf16(hi1, lo1, acc, 0,0,0);
    acc = __builtin_amdgcn_mfma_f32_32x32x16_bf16(lo0, hi0, acc, 0,0,0);
    acc = __builtin_amdgcn_mfma_f32_32x32x16_bf16(lo1, hi1, acc, 0,0,0);
    #pragma unroll
    for (int q = 0; q < 16; q++) {
      int row = (q & 3) + 8*(q >> 2) + 4*h;
      Ssh[row*33 + r] = acc[q] + ((row == r) ? 1.0f : 0.0f);
    }
    float a[32];
    #pragma unroll
    for (int j = 0; j < 32; j++) a[j] = Ssh[r*33 + j];   // lane r holds row r
    float ldsum = 0.0f;
    #pragma unroll
    for (int j = 0; j < 32; j++) {
      float dd = __shfl(a[j], j);
      float inv = rsqrtf(dd);
      float sq = dd * inv;
      ldsum += __logf(sq);
      float l = a[j] * inv;
      #pragma unroll
      for (int e = j+1; e < 32; e++) {
        float le = __shfl(l, e);
        a[e] = (r >= e) ? fmaf(-l, le, a[e]) : a[e];
      }
      a[j] = (r == j) ? sq : ((r > j) ? l : a[j]);
    }
    #pragma unroll
    for (int j = 0; j < 32; j++) Ssh[r*33 + j] = a[j];
    // register-recurrence inversion: lane r owns column r of B = L^-1
    float bv[32];
    #pragma unroll
    for (int d = 0; d < 32; d++) {
      float s0 = (d == r) ? 1.0f : 0.0f, s1 = 0.0f;
      #pragma unroll
      for (int j = 0; j + 1 < d; j += 2) {
        s0 = fmaf(-Ssh[d*33 + j],     bv[j],   s0);
        s1 = fmaf(-Ssh[d*33 + j + 1], bv[j+1], s1);
      }
      if (d & 1) s0 = fmaf(-Ssh[d*33 + (d-1)], bv[d-1], s0);
      bv[d] = __fdividef(s0 + s1, Ssh[d*33 + d]);
    }
    #pragma unroll
    for (int d = 0; d < 32; d++) Ssh[d*33 + r] = bv[d];
    float t0[8], t1[8];
    #pragma unroll
    for (int j = 0; j < 8; j++) {
      t0[j] = Ssh[r*33 + h*8 + j];
      t1[j] = Ssh[r*33 + 16 + h*8 + j];
    }
    uint4 s0 = make_uint4(bfh(t0[0])|(bfh(t0[1])<<16), bfh(t0[2])|(bfh(t0[3])<<16),
                          bfh(t0[4])|(bfh(t0[5])<<16), bfh(t0[6])|(bfh(t0[7])<<16));
    uint4 s1 = make_uint4(bfh(t1[0])|(bfh(t1[1])<<16), bfh(t1[2])|(bfh(t1[3])<<16),
                          bfh(t1[4])|(bfh(t1[5])<<16), bfh(t1[6])|(bfh(t1[7])<<16));
    Afrag[(k*2 + 0)*64 + lane] = s0;
    Afrag[(k*2 + 1)*64 + lane] = s1;
    // g = 2*Ahi^T*Ahi*mu, c = ||Ahi mu||^2 — hi-only, consistent with fragments
    const float* mk = means + k*32;
    float wr = 0.0f;
    #pragma unroll
    for (int j = 0; j < 32; j++) wr = fmaf(bfhf(Ssh[r*33 + j]), mk[j], wr);
    float c = wr*wr;
    #pragma unroll
    for (int off = 16; off > 0; off >>= 1) c += __shfl_xor(c, off);
    float gd = 0.0f;
    #pragma unroll
    for (int rr = 0; rr < 32; rr++)
      gd = fmaf(bfhf(bv[rr]), __shfl(wr, rr), gd);     // bv[rr] = B[rr][r]
    if (h == 0) gbuf[k*32 + r] = 2.0f*gd;
    if (lane == 0) {
      float wk = wts[k];
      float ld2 = 2.0f*ldsum + DLOG2PIF;
      Kc[k] = LOG2E*(SHIFT - 0.5f*ld2 - 0.5f*c) + log2f(fabsf(wk));
      Sg[k] = (wk < 0.0f) ? -1.0f : 1.0f;
    }
  } else {
    // --------------------------- pair role ---------------------------
    const int pid = (blockIdx.x - 8)*4 + wv, pi = pid >> 5, pj = pid & 31;
    const float* cpi = chols + (size_t)pi*1024 + r*32;
    const float* cpj = chols + (size_t)pj*1024 + r*32;
    float4 ia = *(const float4*)(cpi + h*8);
    float4 ib = *(const float4*)(cpi + h*8 + 4);
    float4 ic = *(const float4*)(cpi + 16 + h*8);
    float4 id = *(const float4*)(cpi + 16 + h*8 + 4);
    float4 ja = *(const float4*)(cpj + h*8);
    float4 jb = *(const float4*)(cpj + h*8 + 4);
    float4 jc = *(const float4*)(cpj + 16 + h*8);
    float4 jd = *(const float4*)(cpj + 16 + h*8 + 4);
    float vi0[8] = {ia.x,ia.y,ia.z,ia.w,ib.x,ib.y,ib.z,ib.w};
    float vi1[8] = {ic.x,ic.y,ic.z,ic.w,id.x,id.y,id.z,id.w};
    float vj0[8] = {ja.x,ja.y,ja.z,ja.w,jb.x,jb.y,jb.z,jb.w};
    float vj1[8] = {jc.x,jc.y,jc.z,jc.w,jd.x,jd.y,jd.z,jd.w};
    short8 I0h,I0l,I1h,I1l,J0h,J0l,J1h,J1l;
    #pragma unroll
    for (int j = 0; j < 8; j++) {
      I0h[j]=(short)bfh(vi0[j]); I0l[j]=(short)bfh(vi0[j]-bfhf(vi0[j]));
      I1h[j]=(short)bfh(vi1[j]); I1l[j]=(short)bfh(vi1[j]-bfhf(vi1[j]));
      J0h[j]=(short)bfh(vj0[j]); J0l[j]=(short)bfh(vj0[j]-bfhf(vj0[j]));
      J1h[j]=(short)bfh(vj1[j]); J1l[j]=(short)bfh(vj1[j]-bfhf(vj1[j]));
    }
    f32x16 pacc = {};
    pacc = __builtin_amdgcn_mfma_f32_32x32x16_bf16(I0h, I0h, pacc, 0,0,0);
    pacc = __builtin_amdgcn_mfma_f32_32x32x16_bf16(I1h, I1h, pacc, 0,0,0);
    pacc = __builtin_amdgcn_mfma_f32_32x32x16_bf16(I0h, I0l, pacc, 0,0,0);
    pacc = __builtin_amdgcn_mfma_f32_32x32x16_bf16(I1h, I1l, pacc, 0,0,0);
    pacc = __builtin_amdgcn_mfma_f32_32x32x16_bf16(I0l, I0h, pacc, 0,0,0);
    pacc = __builtin_amdgcn_mfma_f32_32x32x16_bf16(I1l, I1h, pacc, 0,0,0);
    pacc = __builtin_amdgcn_mfma_f32_32x32x16_bf16(J0h, J0h, pacc, 0,0,0);
    pacc = __builtin_amdgcn_mfma_f32_32x32x16_bf16(J1h, J1h, pacc, 0,0,0);
    pacc = __builtin_amdgcn_mfma_f32_32x32x16_bf16(J0h, J0l, pacc, 0,0,0);
    pacc = __builtin_amdgcn_mfma_f32_32x32x16_bf16(J1h, J1l, pacc, 0,0,0);
    pacc = __builtin_amdgcn_mfma_f32_32x32x16_bf16(J0l, J0h, pacc, 0,0,0);
    pacc = __builtin_amdgcn_mfma_f32_32x32x16_bf16(J1l, J1h, pacc, 0,0,0);
    #pragma unroll
    for (int q = 0; q < 16; q++) {
      int row = (q & 3) + 8*(q >> 2) + 4*h;
      Ssh[row*33 + r] = pacc[q] + ((row == r) ? 2.0f : 0.0f);
    }
    float a[32];
    #pragma unroll
    for (int j = 0; j < 32; j++) a[j] = Ssh[r*33 + j];
    #pragma unroll
    for (int j = 0; j < 32; j++) {
      float dd = __shfl(a[j], j);
      float inv = __frsqrt_rn(dd);
      float sq = dd * inv;
      float l = a[j] * inv;
      #pragma unroll
      for (int e = j+1; e < 32; e++) {
        float le = __shfl(l, e);
        a[e] = (r >= e) ? fmaf(-l, le, a[e]) : a[e];
      }
      a[j] = (r == j) ? sq : ((r > j) ? l : a[j]);
    }
    float acc2 = means[pi*32 + r] - means[pj*32 + r];
    float maha = 0.0f, ldsum = 0.0f;
    #pragma unroll
    for (int d = 0; d < 32; d++) {
      float dd = __shfl(a[d], d);
      float yd = __shfl(acc2, d) / dd;
      maha = fmaf(yd, yd, maha);
      ldsum += __logf(dd);
      acc2 = (r > d) ? fmaf(-a[d], yd, acc2) : acc2;
    }
    if (lane == 0) {
      double vd = -0.5 * ((double)maha + 2.0*(double)ldsum + DLOG2PI);
      zterm[pid] = (double)wts[pi] * (double)wts[pj] * exp(vd);
    }
  }
}

// ===== kernel 2: points only — barrier-free, fragments direct from L2 =============
// 512 blocks x 4 waves x 2 sets x 32 pts. No LDS staging: Afrag (64 KB) is L2-hot
// and every wave streams it with a 2-cluster-deep register prefetch.
__global__ __launch_bounds__(256) void work_kernel(
    const float* __restrict__ X,
    const uint4* __restrict__ Afrag, const float* __restrict__ gbuf,
    const float* __restrict__ Kc, const float* __restrict__ Sg,
    const double* __restrict__ zterm, double* __restrict__ partials,
    unsigned* __restrict__ ticket, float* __restrict__ out)
{
  __shared__ float K2sh[32], sksh[32];
  __shared__ double redd[4], redz[4];
  __shared__ unsigned lastFlag;
  const int tid = threadIdx.x, wv = tid >> 6, lane = tid & 63;
  const int r = lane & 31, h = lane >> 5;
  if (tid < 32) { K2sh[tid] = Kc[tid]; sksh[tid] = Sg[tid]; }
  const int n0 = blockIdx.x*256 + wv*64 + r;       // set0; set1 = n0+32
  short8 xh00, xh01, xh10, xh11;
  {
    const float* xp0 = X + (size_t)n0*32;
    const float* xp1 = X + (size_t)(n0+32)*32;
    float4 fa = *(const float4*)(xp0 + h*8);
    float4 fb = *(const float4*)(xp0 + h*8 + 4);
    float4 fc = *(const float4*)(xp0 + 16 + h*8);
    float4 fd = *(const float4*)(xp0 + 16 + h*8 + 4);
    float4 ga = *(const float4*)(xp1 + h*8);
    float4 gb = *(const float4*)(xp1 + h*8 + 4);
    float4 gc = *(const float4*)(xp1 + 16 + h*8);
    float4 gd = *(const float4*)(xp1 + 16 + h*8 + 4);
    float v00[8] = {fa.x,fa.y,fa.z,fa.w,fb.x,fb.y,fb.z,fb.w};
    float v01[8] = {fc.x,fc.y,fc.z,fc.w,fd.x,fd.y,fd.z,fd.w};
    float v10[8] = {ga.x,ga.y,ga.z,ga.w,gb.x,gb.y,gb.z,gb.w};
    float v11[8] = {gc.x,gc.y,gc.z,gc.w,gd.x,gd.y,gd.z,gd.w};
    #pragma unroll
    for (int j = 0; j < 8; j++) {
      xh00[j] = (short)bfh(v00[j]);  xh01[j] = (short)bfh(v01[j]);
      xh10[j] = (short)bfh(v10[j]);  xh11[j] = (short)bfh(v11[j]);
    }
  }
  __syncthreads();                                 // K2sh/sksh ready (only barrier)
  // amortized g-matvec for both sets
  f32x16 accg0 = {}, accg1 = {};
  {
    const float* gp = gbuf + r*32 + h*8;
    float4 ga = *(const float4*)(gp);
    float4 gb = *(const float4*)(gp + 4);
    float4 gc = *(const float4*)(gp + 16);
    float4 gd = *(const float4*)(gp + 20);
    float g0[8] = {ga.x,ga.y,ga.z,ga.w,gb.x,gb.y,gb.z,gb.w};
    float g1[8] = {gc.x,gc.y,gc.z,gc.w,gd.x,gd.y,gd.z,gd.w};
    short8 Gh0, Gl0, Gh1, Gl1;
    #pragma unroll
    for (int j = 0; j < 8; j++) {
      Gh0[j] = (short)bfh(g0[j]); Gl0[j] = (short)bfh(g0[j] - bfhf(g0[j]));
      Gh1[j] = (short)bfh(g1[j]); Gl1[j] = (short)bfh(g1[j] - bfhf(g1[j]));
    }
    accg0 = __builtin_amdgcn_mfma_f32_32x32x16_bf16(Gh0, xh00, accg0, 0,0,0);
    accg0 = __builtin_amdgcn_mfma_f32_32x32x16_bf16(Gl0, xh00, accg0, 0,0,0);
    accg0 = __builtin_amdgcn_mfma_f32_32x32x16_bf16(Gh1, xh01, accg0, 0,0,0);
    accg0 = __builtin_amdgcn_mfma_f32_32x32x16_bf16(Gl1, xh01, accg0, 0,0,0);
    accg1 = __builtin_amdgcn_mfma_f32_32x32x16_bf16(Gh0, xh10, accg1, 0,0,0);
    accg1 = __builtin_amdgcn_mfma_f32_32x32x16_bf16(Gl0, xh10, accg1, 0,0,0);
    accg1 = __builtin_amdgcn_mfma_f32_32x32x16_bf16(Gh1, xh11, accg1, 0,0,0);
    accg1 = __builtin_amdgcn_mfma_f32_32x32x16_bf16(Gl1, xh11, accg1, 0,0,0);
  }
  // main sweep: direct L2 fragment loads, 2-deep register prefetch, no barriers
  const short8* ab = (const short8*)Afrag + lane;
  short8 fA0 = ab[0*128], fA1 = ab[0*128 + 64];
  short8 fB0 = ab[1*128], fB1 = ab[1*128 + 64];
  float sF0 = 0.0f, sF1 = 0.0f;
  #pragma unroll
  for (int kk = 0; kk < 32; kk++) {
    short8 c0, c1;
    if ((kk & 1) == 0) { c0 = fA0; c1 = fA1; } else { c0 = fB0; c1 = fB1; }
    if (kk + 2 < 32) {                             // prefetch cluster kk+2
      if ((kk & 1) == 0) { fA0 = ab[(kk+2)*128]; fA1 = ab[(kk+2)*128 + 64]; }
      else               { fB0 = ab[(kk+2)*128]; fB1 = ab[(kk+2)*128 + 64]; }
    }
    const float Kk = K2sh[kk], sk = sksh[kk];
    f32x16 acc0 = {}, acc1 = {};
    acc0 = __builtin_amdgcn_mfma_f32_32x32x16_bf16(c0, xh00, acc0, 0,0,0);
    acc0 = __builtin_amdgcn_mfma_f32_32x32x16_bf16(c1, xh01, acc0, 0,0,0);
    acc1 = __builtin_amdgcn_mfma_f32_32x32x16_bf16(c0, xh10, acc1, 0,0,0);
    acc1 = __builtin_amdgcn_mfma_f32_32x32x16_bf16(c1, xh11, acc1, 0,0,0);
    float m0a=0.f, m0b=0.f, m0c=0.f, m0d=0.f;
    float m1a=0.f, m1b=0.f, m1c=0.f, m1d=0.f;
    #pragma unroll
    for (int q = 0; q < 4; q++) {                  // 4-way split: dep depth 4
      m0a = fmaf(acc0[q],    acc0[q],    m0a);
      m0b = fmaf(acc0[q+4],  acc0[q+4],  m0b);
      m0c = fmaf(acc0[q+8],  acc0[q+8],  m0c);
      m0d = fmaf(acc0[q+12], acc0[q+12], m0d);
      m1a = fmaf(acc1[q],    acc1[q],    m1a);
      m1b = fmaf(acc1[q+4],  acc1[q+4],  m1b);
      m1c = fmaf(acc1[q+8],  acc1[q+8],  m1c);
      m1d = fmaf(acc1[q+12], acc1[q+12], m1d);
    }
    const int qg = (kk & 3) | (((kk >> 3) & 3) << 2);
    const int hneed = (kk >> 2) & 1;
    float m0 = (m0a + m0b) + (m0c + m0d) - ((h == hneed) ? accg0[qg] : 0.0f);
    float m1 = (m1a + m1b) + (m1c + m1d) - ((h == hneed) ? accg1[qg] : 0.0f);
    m0 += __shfl_xor(m0, 32);
    m1 += __shfl_xor(m1, 32);
    sF0 = fmaf(sk, exp2f(fmaf(m0, NEGHALF_LOG2E, Kk)), sF0);
    sF1 = fmaf(sk, exp2f(fmaf(m1, NEGHALF_LOG2E, Kk)), sF1);
  }
  double Tp = (double)sF0*(double)sF0 + (double)sF1*(double)sF1;
  if (lane >= 32) Tp = 0.0;                        // upper halves duplicate
  #pragma unroll
  for (int off = 32; off > 0; off >>= 1) Tp += __shfl_down(Tp, off);
  if (lane == 0) redd[wv] = Tp;
  __syncthreads();
  if (tid == 0) partials[blockIdx.x] = redd[0] + redd[1] + redd[2] + redd[3];
  // ================= end-of-kernel ticket + fused final ====================
  __syncthreads();
  if (tid == 0) {
    __threadfence();
    lastFlag = (atomicAdd(ticket, 1u) == GRIDW - 1) ? 1u : 0u;
  }
  __syncthreads();
  if (lastFlag) {
    __threadfence();
    double t = 0.0, z = 0.0;
    for (int p = tid; p < NPTB; p += 256) t += partials[p];
    for (int p = tid; p < 1024; p += 256) z += zterm[p];
    #pragma unroll
    for (int off = 32; off > 0; off >>= 1) {
      t += __shfl_down(t, off);
      z += __shfl_down(z, off);
    }
    if (lane == 0) { redd[wv] = t; redz[wv] = z; }
    __syncthreads();
    if (tid == 0) {
      t = redd[0] + redd[1] + redd[2] + redd[3];
      z = redz[0] + redz[1] + redz[2] + redz[3];
      double logT = log(t) - 2.0*(double)SHIFT;
      double logz = log(z);
      out[0] = (float)((logz - logT) / (double)NPTS);
    }
  }
}

extern "C" void kernel_launch(void* const* d_in, const int* in_sizes, int n_in,
                              void* d_out, int out_size, void* d_ws, size_t ws_size,
                              hipStream_t stream) {
  const float* X     = (const float*)d_in[0];
  const float* means = (const float*)d_in[1];
  const float* chols = (const float*)d_in[2];
  const float* wts   = (const float*)d_in[3];
  float* out = (float*)d_out;
  char* ws = (char*)d_ws;
  uint4*    Afrag    = (uint4*)ws;                  // 65536
  float*    gbuf     = (float*)(ws + 65536);        // 4096  -> 69632
  float*    Kc       = (float*)(ws + 69632);        // 128   -> 69760
  float*    Sg       = (float*)(ws + 69760);        // 128   -> 69888
  double*   zterm    = (double*)(ws + 69888);       // 8192  -> 78080
  double*   partials = (double*)(ws + 78080);       // 4096  -> 82176
  unsigned* ticket   = (unsigned*)(ws + 82176);     // 4     -> 82180

  setup_kernel<<<8 + NPRB, 256, 0, stream>>>(means, chols, wts, Afrag, gbuf,
                                             Kc, Sg, zterm, ticket);
  work_kernel<<<GRIDW, 256, 0, stream>>>(X, Afrag, gbuf, Kc, Sg,
                                         zterm, partials, ticket, out);
}

// Round 4
// 113.956 us; speedup vs baseline: 1.3546x; 1.0278x over previous
//
#include <hip/hip_runtime.h>
#include <math.h>

#define NPTS  131072
#define NPTB  512          // point blocks: 256 thr = 4 waves x 2 sets x 32 pts
#define NPRB  256          // pair blocks folded into setup kernel (blocks 8..263)
#define GRIDW NPTB         // work-kernel grid (points only)
#define DLOG2PIF 58.8120661f
#define DLOG2PI  58.81206612467475
#define SHIFT 92.0f
#define NEGHALF_LOG2E -0.72134752044f
#define LOG2E 1.44269504089f

typedef __attribute__((ext_vector_type(8)))  short short8;
typedef __attribute__((ext_vector_type(16))) float f32x16;

static __device__ __forceinline__ unsigned bfh(float f) {    // fp32 -> bf16 bits (RNE)
  unsigned u = __float_as_uint(f);
  return (u + 0x7FFFu + ((u >> 16) & 1u)) >> 16;
}
static __device__ __forceinline__ float bfhf(float f) {
  return __uint_as_float(bfh(f) << 16);
}

// ===== kernel 1: setup (blocks 0..7, 1 cluster/wave) + pairs (blocks 8..263) ======
// Pairs depend only on inputs -> they overlap setup's serial Cholesky window.
__global__ __launch_bounds__(256) void setup_kernel(
    const float* __restrict__ means, const float* __restrict__ chols,
    const float* __restrict__ wts,
    uint4* __restrict__ Afrag, float* __restrict__ gbuf,
    float* __restrict__ Kc, float* __restrict__ Sg,
    double* __restrict__ zterm, unsigned* __restrict__ ticket)
{
  const int tid = threadIdx.x, wv = tid >> 6, lane = tid & 63;
  const int r = lane & 31, h = lane >> 5;
  __shared__ float SshA[4][1056];
  float* Ssh = SshA[wv];
  if (blockIdx.x < 8) {
    // --------------------------- setup role ---------------------------
    const int k = blockIdx.x*4 + wv;
    if (blockIdx.x == 0 && tid == 0) *ticket = 0u;
    const float* cp = chols + (size_t)k*1024 + r*32;
    float4 fa = *(const float4*)(cp + h*8);
    float4 fb = *(const float4*)(cp + h*8 + 4);
    float4 fc = *(const float4*)(cp + 16 + h*8);
    float4 fd = *(const float4*)(cp + 16 + h*8 + 4);
    float v0[8] = {fa.x,fa.y,fa.z,fa.w,fb.x,fb.y,fb.z,fb.w};
    float v1[8] = {fc.x,fc.y,fc.z,fc.w,fd.x,fd.y,fd.z,fd.w};
    short8 hi0, hi1, lo0, lo1;
    #pragma unroll
    for (int j = 0; j < 8; j++) {
      hi0[j] = (short)bfh(v0[j]);  lo0[j] = (short)bfh(v0[j] - bfhf(v0[j]));
      hi1[j] = (short)bfh(v1[j]);  lo1[j] = (short)bfh(v1[j] - bfhf(v1[j]));
    }
    f32x16 acc = {};
    acc = __builtin_amdgcn_mfma_f32_32x32x16_bf16(hi0, hi0, acc, 0,0,0);
    acc = __builtin_amdgcn_mfma_f32_32x32x16_bf16(hi1, hi1, acc, 0,0,0);
    acc = __builtin_amdgcn_mfma_f32_32x32x16_bf16(hi0, lo0, acc, 0,0,0);
    acc = __builtin_amdgcn_mfma_f32_32x32x16_bf16(hi1, lo1, acc, 0,0,0);
    acc = __builtin_amdgcn_mfma_f32_32x32x16_bf16(lo0, hi0, acc, 0,0,0);
    acc = __builtin_amdgcn_mfma_f32_32x32x16_bf16(lo1, hi1, acc, 0,0,0);
    #pragma unroll
    for (int q = 0; q < 16; q++) {
      int row = (q & 3) + 8*(q >> 2) + 4*h;
      Ssh[row*33 + r] = acc[q] + ((row == r) ? 1.0f : 0.0f);
    }
    float a[32];
    #pragma unroll
    for (int j = 0; j < 32; j++) a[j] = Ssh[r*33 + j];   // lane r holds row r
    float ldsum = 0.0f;
    #pragma unroll
    for (int j = 0; j < 32; j++) {
      float dd = __shfl(a[j], j);
      float inv = rsqrtf(dd);
      float sq = dd * inv;
      ldsum += __logf(sq);
      float l = a[j] * inv;
      #pragma unroll
      for (int e = j+1; e < 32; e++) {
        float le = __shfl(l, e);
        a[e] = (r >= e) ? fmaf(-l, le, a[e]) : a[e];
      }
      a[j] = (r == j) ? sq : ((r > j) ? l : a[j]);
    }
    #pragma unroll
    for (int j = 0; j < 32; j++) Ssh[r*33 + j] = a[j];
    // register-recurrence inversion: lane r owns column r of B = L^-1
    float bv[32];
    #pragma unroll
    for (int d = 0; d < 32; d++) {
      float s0 = (d == r) ? 1.0f : 0.0f, s1 = 0.0f;
      #pragma unroll
      for (int j = 0; j + 1 < d; j += 2) {
        s0 = fmaf(-Ssh[d*33 + j],     bv[j],   s0);
        s1 = fmaf(-Ssh[d*33 + j + 1], bv[j+1], s1);
      }
      if (d & 1) s0 = fmaf(-Ssh[d*33 + (d-1)], bv[d-1], s0);
      bv[d] = __fdividef(s0 + s1, Ssh[d*33 + d]);
    }
    #pragma unroll
    for (int d = 0; d < 32; d++) Ssh[d*33 + r] = bv[d];
    float t0[8], t1[8];
    #pragma unroll
    for (int j = 0; j < 8; j++) {
      t0[j] = Ssh[r*33 + h*8 + j];
      t1[j] = Ssh[r*33 + 16 + h*8 + j];
    }
    uint4 s0 = make_uint4(bfh(t0[0])|(bfh(t0[1])<<16), bfh(t0[2])|(bfh(t0[3])<<16),
                          bfh(t0[4])|(bfh(t0[5])<<16), bfh(t0[6])|(bfh(t0[7])<<16));
    uint4 s1 = make_uint4(bfh(t1[0])|(bfh(t1[1])<<16), bfh(t1[2])|(bfh(t1[3])<<16),
                          bfh(t1[4])|(bfh(t1[5])<<16), bfh(t1[6])|(bfh(t1[7])<<16));
    Afrag[(k*2 + 0)*64 + lane] = s0;
    Afrag[(k*2 + 1)*64 + lane] = s1;
    // g = 2*Ahi^T*Ahi*mu, c = ||Ahi mu||^2 — hi-only, consistent with fragments
    const float* mk = means + k*32;
    float wr = 0.0f;
    #pragma unroll
    for (int j = 0; j < 32; j++) wr = fmaf(bfhf(Ssh[r*33 + j]), mk[j], wr);
    float c = wr*wr;
    #pragma unroll
    for (int off = 16; off > 0; off >>= 1) c += __shfl_xor(c, off);
    float gd = 0.0f;
    #pragma unroll
    for (int rr = 0; rr < 32; rr++)
      gd = fmaf(bfhf(bv[rr]), __shfl(wr, rr), gd);     // bv[rr] = B[rr][r]
    if (h == 0) gbuf[k*32 + r] = 2.0f*gd;
    if (lane == 0) {
      float wk = wts[k];
      float ld2 = 2.0f*ldsum + DLOG2PIF;
      Kc[k] = LOG2E*(SHIFT - 0.5f*ld2 - 0.5f*c) + log2f(fabsf(wk));
      Sg[k] = (wk < 0.0f) ? -1.0f : 1.0f;
    }
  } else {
    // --------------------------- pair role ---------------------------
    const int pid = (blockIdx.x - 8)*4 + wv, pi = pid >> 5, pj = pid & 31;
    const float* cpi = chols + (size_t)pi*1024 + r*32;
    const float* cpj = chols + (size_t)pj*1024 + r*32;
    float4 ia = *(const float4*)(cpi + h*8);
    float4 ib = *(const float4*)(cpi + h*8 + 4);
    float4 ic = *(const float4*)(cpi + 16 + h*8);
    float4 id = *(const float4*)(cpi + 16 + h*8 + 4);
    float4 ja = *(const float4*)(cpj + h*8);
    float4 jb = *(const float4*)(cpj + h*8 + 4);
    float4 jc = *(const float4*)(cpj + 16 + h*8);
    float4 jd = *(const float4*)(cpj + 16 + h*8 + 4);
    float vi0[8] = {ia.x,ia.y,ia.z,ia.w,ib.x,ib.y,ib.z,ib.w};
    float vi1[8] = {ic.x,ic.y,ic.z,ic.w,id.x,id.y,id.z,id.w};
    float vj0[8] = {ja.x,ja.y,ja.z,ja.w,jb.x,jb.y,jb.z,jb.w};
    float vj1[8] = {jc.x,jc.y,jc.z,jc.w,jd.x,jd.y,jd.z,jd.w};
    short8 I0h,I0l,I1h,I1l,J0h,J0l,J1h,J1l;
    #pragma unroll
    for (int j = 0; j < 8; j++) {
      I0h[j]=(short)bfh(vi0[j]); I0l[j]=(short)bfh(vi0[j]-bfhf(vi0[j]));
      I1h[j]=(short)bfh(vi1[j]); I1l[j]=(short)bfh(vi1[j]-bfhf(vi1[j]));
      J0h[j]=(short)bfh(vj0[j]); J0l[j]=(short)bfh(vj0[j]-bfhf(vj0[j]));
      J1h[j]=(short)bfh(vj1[j]); J1l[j]=(short)bfh(vj1[j]-bfhf(vj1[j]));
    }
    f32x16 pacc = {};
    pacc = __builtin_amdgcn_mfma_f32_32x32x16_bf16(I0h, I0h, pacc, 0,0,0);
    pacc = __builtin_amdgcn_mfma_f32_32x32x16_bf16(I1h, I1h, pacc, 0,0,0);
    pacc = __builtin_amdgcn_mfma_f32_32x32x16_bf16(I0h, I0l, pacc, 0,0,0);
    pacc = __builtin_amdgcn_mfma_f32_32x32x16_bf16(I1h, I1l, pacc, 0,0,0);
    pacc = __builtin_amdgcn_mfma_f32_32x32x16_bf16(I0l, I0h, pacc, 0,0,0);
    pacc = __builtin_amdgcn_mfma_f32_32x32x16_bf16(I1l, I1h, pacc, 0,0,0);
    pacc = __builtin_amdgcn_mfma_f32_32x32x16_bf16(J0h, J0h, pacc, 0,0,0);
    pacc = __builtin_amdgcn_mfma_f32_32x32x16_bf16(J1h, J1h, pacc, 0,0,0);
    pacc = __builtin_amdgcn_mfma_f32_32x32x16_bf16(J0h, J0l, pacc, 0,0,0);
    pacc = __builtin_amdgcn_mfma_f32_32x32x16_bf16(J1h, J1l, pacc, 0,0,0);
    pacc = __builtin_amdgcn_mfma_f32_32x32x16_bf16(J0l, J0h, pacc, 0,0,0);
    pacc = __builtin_amdgcn_mfma_f32_32x32x16_bf16(J1l, J1h, pacc, 0,0,0);
    #pragma unroll
    for (int q = 0; q < 16; q++) {
      int row = (q & 3) + 8*(q >> 2) + 4*h;
      Ssh[row*33 + r] = pacc[q] + ((row == r) ? 2.0f : 0.0f);
    }
    float a[32];
    #pragma unroll
    for (int j = 0; j < 32; j++) a[j] = Ssh[r*33 + j];
    #pragma unroll
    for (int j = 0; j < 32; j++) {
      float dd = __shfl(a[j], j);
      float inv = __frsqrt_rn(dd);
      float sq = dd * inv;
      float l = a[j] * inv;
      #pragma unroll
      for (int e = j+1; e < 32; e++) {
        float le = __shfl(l, e);
        a[e] = (r >= e) ? fmaf(-l, le, a[e]) : a[e];
      }
      a[j] = (r == j) ? sq : ((r > j) ? l : a[j]);
    }
    float acc2 = means[pi*32 + r] - means[pj*32 + r];
    float maha = 0.0f, ldsum = 0.0f;
    #pragma unroll
    for (int d = 0; d < 32; d++) {
      float dd = __shfl(a[d], d);
      float yd = __shfl(acc2, d) / dd;
      maha = fmaf(yd, yd, maha);
      ldsum += __logf(dd);
      acc2 = (r > d) ? fmaf(-a[d], yd, acc2) : acc2;
    }
    if (lane == 0) {
      double vd = -0.5 * ((double)maha + 2.0*(double)ldsum + DLOG2PI);
      zterm[pid] = (double)wts[pi] * (double)wts[pj] * exp(vd);
    }
  }
}

// ===== kernel 2: points — LDS-resident fragment table, single barrier ============
// 512 blocks x 4 waves x 2 sets x 32 pts; 64 KB table staged once (2 blocks/CU is
// grid-capped anyway, so the LDS is free). Sweep reads via ds_read_b128 (~12cyc)
// with 1-deep prefetch; no barriers, no L2 latency in the cluster loop.
__global__ __launch_bounds__(256) void work_kernel(
    const float* __restrict__ X,
    const uint4* __restrict__ Afrag, const float* __restrict__ gbuf,
    const float* __restrict__ Kc, const float* __restrict__ Sg,
    const double* __restrict__ zterm, double* __restrict__ partials,
    unsigned* __restrict__ ticket, float* __restrict__ out)
{
  __shared__ __align__(16) uint4 fsh[4096];        // 64 KB fragment table
  __shared__ float K2sh[32], sksh[32];
  __shared__ double redd[4], redz[4];
  __shared__ unsigned lastFlag;
  const int tid = threadIdx.x, wv = tid >> 6, lane = tid & 63;
  const int r = lane & 31, h = lane >> 5;
  if (tid < 32) { K2sh[tid] = Kc[tid]; sksh[tid] = Sg[tid]; }
  const int n0 = blockIdx.x*256 + wv*64 + r;       // set0; set1 = n0+32
  // ---- issue table staging round 1 (overlaps X/g loads below) ----
  uint4 st[8];
  #pragma unroll
  for (int i = 0; i < 8; i++) st[i] = Afrag[i*256 + tid];
  short8 xh00, xh01, xh10, xh11;
  {
    const float* xp0 = X + (size_t)n0*32;
    const float* xp1 = X + (size_t)(n0+32)*32;
    float4 fa = *(const float4*)(xp0 + h*8);
    float4 fb = *(const float4*)(xp0 + h*8 + 4);
    float4 fc = *(const float4*)(xp0 + 16 + h*8);
    float4 fd = *(const float4*)(xp0 + 16 + h*8 + 4);
    float4 ga = *(const float4*)(xp1 + h*8);
    float4 gb = *(const float4*)(xp1 + h*8 + 4);
    float4 gc = *(const float4*)(xp1 + 16 + h*8);
    float4 gd = *(const float4*)(xp1 + 16 + h*8 + 4);
    float v00[8] = {fa.x,fa.y,fa.z,fa.w,fb.x,fb.y,fb.z,fb.w};
    float v01[8] = {fc.x,fc.y,fc.z,fc.w,fd.x,fd.y,fd.z,fd.w};
    float v10[8] = {ga.x,ga.y,ga.z,ga.w,gb.x,gb.y,gb.z,gb.w};
    float v11[8] = {gc.x,gc.y,gc.z,gc.w,gd.x,gd.y,gd.z,gd.w};
    #pragma unroll
    for (int j = 0; j < 8; j++) {
      xh00[j] = (short)bfh(v00[j]);  xh01[j] = (short)bfh(v01[j]);
      xh10[j] = (short)bfh(v10[j]);  xh11[j] = (short)bfh(v11[j]);
    }
  }
  #pragma unroll
  for (int i = 0; i < 8; i++) fsh[i*256 + tid] = st[i];
  #pragma unroll
  for (int i = 0; i < 8; i++) st[i] = Afrag[(i+8)*256 + tid];
  // ---- amortized g-matvec (register-only; overlaps staging round 2) ----
  f32x16 accg0 = {}, accg1 = {};
  {
    const float* gp = gbuf + r*32 + h*8;
    float4 ga = *(const float4*)(gp);
    float4 gb = *(const float4*)(gp + 4);
    float4 gc = *(const float4*)(gp + 16);
    float4 gd = *(const float4*)(gp + 20);
    float g0[8] = {ga.x,ga.y,ga.z,ga.w,gb.x,gb.y,gb.z,gb.w};
    float g1[8] = {gc.x,gc.y,gc.z,gc.w,gd.x,gd.y,gd.z,gd.w};
    short8 Gh0, Gl0, Gh1, Gl1;
    #pragma unroll
    for (int j = 0; j < 8; j++) {
      Gh0[j] = (short)bfh(g0[j]); Gl0[j] = (short)bfh(g0[j] - bfhf(g0[j]));
      Gh1[j] = (short)bfh(g1[j]); Gl1[j] = (short)bfh(g1[j] - bfhf(g1[j]));
    }
    accg0 = __builtin_amdgcn_mfma_f32_32x32x16_bf16(Gh0, xh00, accg0, 0,0,0);
    accg0 = __builtin_amdgcn_mfma_f32_32x32x16_bf16(Gl0, xh00, accg0, 0,0,0);
    accg0 = __builtin_amdgcn_mfma_f32_32x32x16_bf16(Gh1, xh01, accg0, 0,0,0);
    accg0 = __builtin_amdgcn_mfma_f32_32x32x16_bf16(Gl1, xh01, accg0, 0,0,0);
    accg1 = __builtin_amdgcn_mfma_f32_32x32x16_bf16(Gh0, xh10, accg1, 0,0,0);
    accg1 = __builtin_amdgcn_mfma_f32_32x32x16_bf16(Gl0, xh10, accg1, 0,0,0);
    accg1 = __builtin_amdgcn_mfma_f32_32x32x16_bf16(Gh1, xh11, accg1, 0,0,0);
    accg1 = __builtin_amdgcn_mfma_f32_32x32x16_bf16(Gl1, xh11, accg1, 0,0,0);
  }
  #pragma unroll
  for (int i = 0; i < 8; i++) fsh[(i+8)*256 + tid] = st[i];
  __syncthreads();                                 // table + K2sh ready (only barrier)
  // ---- main sweep: LDS fragment reads, 1-deep prefetch, no barriers ----
  const short8* ab = (const short8*)fsh + lane;
  short8 c0 = ab[0], c1 = ab[64];
  float sF0 = 0.0f, sF1 = 0.0f;
  #pragma unroll
  for (int kk = 0; kk < 32; kk++) {
    short8 n0f, n1f;
    if (kk < 31) { n0f = ab[(kk+1)*128]; n1f = ab[(kk+1)*128 + 64]; }
    const float Kk = K2sh[kk], sk = sksh[kk];
    f32x16 acc0 = {}, acc1 = {};
    acc0 = __builtin_amdgcn_mfma_f32_32x32x16_bf16(c0, xh00, acc0, 0,0,0);
    acc0 = __builtin_amdgcn_mfma_f32_32x32x16_bf16(c1, xh01, acc0, 0,0,0);
    acc1 = __builtin_amdgcn_mfma_f32_32x32x16_bf16(c0, xh10, acc1, 0,0,0);
    acc1 = __builtin_amdgcn_mfma_f32_32x32x16_bf16(c1, xh11, acc1, 0,0,0);
    float m0a=0.f, m0b=0.f, m0c=0.f, m0d=0.f;
    float m1a=0.f, m1b=0.f, m1c=0.f, m1d=0.f;
    #pragma unroll
    for (int q = 0; q < 4; q++) {                  // 4-way split: dep depth 4
      m0a = fmaf(acc0[q],    acc0[q],    m0a);
      m0b = fmaf(acc0[q+4],  acc0[q+4],  m0b);
      m0c = fmaf(acc0[q+8],  acc0[q+8],  m0c);
      m0d = fmaf(acc0[q+12], acc0[q+12], m0d);
      m1a = fmaf(acc1[q],    acc1[q],    m1a);
      m1b = fmaf(acc1[q+4],  acc1[q+4],  m1b);
      m1c = fmaf(acc1[q+8],  acc1[q+8],  m1c);
      m1d = fmaf(acc1[q+12], acc1[q+12], m1d);
    }
    const int qg = (kk & 3) | (((kk >> 3) & 3) << 2);
    const int hneed = (kk >> 2) & 1;
    float m0 = (m0a + m0b) + (m0c + m0d) - ((h == hneed) ? accg0[qg] : 0.0f);
    float m1 = (m1a + m1b) + (m1c + m1d) - ((h == hneed) ? accg1[qg] : 0.0f);
    m0 += __shfl_xor(m0, 32);
    m1 += __shfl_xor(m1, 32);
    sF0 = fmaf(sk, exp2f(fmaf(m0, NEGHALF_LOG2E, Kk)), sF0);
    sF1 = fmaf(sk, exp2f(fmaf(m1, NEGHALF_LOG2E, Kk)), sF1);
    c0 = n0f; c1 = n1f;
  }
  double Tp = (double)sF0*(double)sF0 + (double)sF1*(double)sF1;
  if (lane >= 32) Tp = 0.0;                        // upper halves duplicate
  #pragma unroll
  for (int off = 32; off > 0; off >>= 1) Tp += __shfl_down(Tp, off);
  if (lane == 0) redd[wv] = Tp;
  __syncthreads();
  if (tid == 0) partials[blockIdx.x] = redd[0] + redd[1] + redd[2] + redd[3];
  // ================= end-of-kernel ticket + fused final ====================
  __syncthreads();
  if (tid == 0) {
    __threadfence();
    lastFlag = (atomicAdd(ticket, 1u) == GRIDW - 1) ? 1u : 0u;
  }
  __syncthreads();
  if (lastFlag) {
    __threadfence();
    double t = 0.0, z = 0.0;
    for (int p = tid; p < NPTB; p += 256) t += partials[p];
    for (int p = tid; p < 1024; p += 256) z += zterm[p];
    #pragma unroll
    for (int off = 32; off > 0; off >>= 1) {
      t += __shfl_down(t, off);
      z += __shfl_down(z, off);
    }
    if (lane == 0) { redd[wv] = t; redz[wv] = z; }
    __syncthreads();
    if (tid == 0) {
      t = redd[0] + redd[1] + redd[2] + redd[3];
      z = redz[0] + redz[1] + redz[2] + redz[3];
      double logT = log(t) - 2.0*(double)SHIFT;
      double logz = log(z);
      out[0] = (float)((logz - logT) / (double)NPTS);
    }
  }
}

extern "C" void kernel_launch(void* const* d_in, const int* in_sizes, int n_in,
                              void* d_out, int out_size, void* d_ws, size_t ws_size,
                              hipStream_t stream) {
  const float* X     = (const float*)d_in[0];
  const float* means = (const float*)d_in[1];
  const float* chols = (const float*)d_in[2];
  const float* wts   = (const float*)d_in[3];
  float* out = (float*)d_out;
  char* ws = (char*)d_ws;
  uint4*    Afrag    = (uint4*)ws;                  // 65536
  float*    gbuf     = (float*)(ws + 65536);        // 4096  -> 69632
  float*    Kc       = (float*)(ws + 69632);        // 128   -> 69760
  float*    Sg       = (float*)(ws + 69760);        // 128   -> 69888
  double*   zterm    = (double*)(ws + 69888);       // 8192  -> 78080
  double*   partials = (double*)(ws + 78080);       // 4096  -> 82176
  unsigned* ticket   = (unsigned*)(ws + 82176);     // 4     -> 82180

  setup_kernel<<<8 + NPRB, 256, 0, stream>>>(means, chols, wts, Afrag, gbuf,
                                             Kc, Sg, zterm, ticket);
  work_kernel<<<GRIDW, 256, 0, stream>>>(X, Afrag, gbuf, Kc, Sg,
                                         zterm, partials, ticket, out);
}